// Round 1
// baseline (718.527 us; speedup 1.0000x reference)
//
#include <hip/hip_runtime.h>
#include <cstdint>

typedef _Float16 f16;
typedef __attribute__((ext_vector_type(8))) _Float16 half8;
typedef __attribute__((ext_vector_type(2))) _Float16 half2v;
typedef __attribute__((ext_vector_type(4))) float floatx4;

#define M_TOTAL 80000
#define NB      40000
#define DIN     1024
#define LDIM    512
#define DDIM    384

// ---------------- kernel 0: weight transpose + f16 convert ----------------
// WfT[n][k] = Wf[k][n] (512x1024), WaT/WbT[n][k] (384x512)
__global__ void k_prep(const float* __restrict__ Wf, const float* __restrict__ Wa,
                       const float* __restrict__ Wb,
                       f16* __restrict__ WfT, f16* __restrict__ WaT, f16* __restrict__ WbT)
{
    const int gid = blockIdx.x * 256 + threadIdx.x;
    if (gid < 512 * 1024) {
        const int n = gid >> 10, k = gid & 1023;
        WfT[gid] = (f16)Wf[k * 512 + n];
    } else if (gid < 512 * 1024 + 384 * 512) {
        const int g = gid - 512 * 1024;
        const int n = g >> 9, k = g & 511;
        WaT[g] = (f16)Wa[k * 384 + n];
    } else if (gid < 512 * 1024 + 2 * 384 * 512) {
        const int g = gid - 512 * 1024 - 384 * 512;
        const int n = g >> 9, k = g & 511;
        WbT[g] = (f16)Wb[k * 384 + n];
    }
}

// ---------------- kernel 1: h = relu(x @ Wf + bf), f16 out ----------------
// BM=64, BN=512 (full), BK=32; 256 threads = 4 waves, each wave 64x128.
// A-frag: row=lane&15, k=(lane>>4)*8+j ; B-frag: col=lane&15, same k
// C/D: col=lane&15, row=(lane>>4)*4+reg   [per guide §3, m89-verified]
__global__ __launch_bounds__(256, 2) void k_gemm1(
    const float* __restrict__ x, const f16* __restrict__ WfT,
    const float* __restrict__ bf, f16* __restrict__ h)
{
    __shared__ __align__(16) f16 As[64 * 40];    // +8 pad: 2-way bank alias only
    __shared__ __align__(16) f16 Bs[512 * 40];
    const int tid  = threadIdx.x;
    const int wave = tid >> 6;
    const int lane = tid & 63;
    const int lr   = lane & 15;
    const int lq   = lane >> 4;
    const long row0 = (long)blockIdx.x * 64;

    floatx4 acc[4][8] = {};

    const int ra = tid >> 2;        // 0..63 (staging row)
    const int ka = (tid & 3) * 8;   // 0,8,16,24
    const float* xrow = x + (row0 + ra) * DIN + ka;

    for (int kt = 0; kt < DIN / 32; ++kt) {
        const int k0 = kt * 32;
        __syncthreads();
        // stage A: 64x32 fp32 -> f16 (convert in-register)
        {
            const float4* p = (const float4*)(xrow + k0);
            float4 f0 = p[0];
            float4 f1 = p[1];
            half8 hv;
            hv[0] = (f16)f0.x; hv[1] = (f16)f0.y; hv[2] = (f16)f0.z; hv[3] = (f16)f0.w;
            hv[4] = (f16)f1.x; hv[5] = (f16)f1.y; hv[6] = (f16)f1.z; hv[7] = (f16)f1.w;
            *(half8*)&As[ra * 40 + ka] = hv;
        }
        // stage B: 512x32 f16 tile of WfT
        #pragma unroll
        for (int rnd = 0; rnd < 8; ++rnd) {
            const int n = (tid >> 2) + rnd * 64;
            *(half8*)&Bs[n * 40 + ka] = *(const half8*)&WfT[(long)n * DIN + k0 + ka];
        }
        __syncthreads();
        half8 af[4];
        #pragma unroll
        for (int ti = 0; ti < 4; ++ti)
            af[ti] = *(const half8*)&As[(ti * 16 + lr) * 40 + lq * 8];
        #pragma unroll
        for (int tj = 0; tj < 8; ++tj) {
            half8 bfrag = *(const half8*)&Bs[(wave * 128 + tj * 16 + lr) * 40 + lq * 8];
            #pragma unroll
            for (int ti = 0; ti < 4; ++ti)
                acc[ti][tj] = __builtin_amdgcn_mfma_f32_16x16x32_f16(af[ti], bfrag, acc[ti][tj], 0, 0, 0);
        }
    }
    // epilogue: +bias, relu, f16 store
    #pragma unroll
    for (int tj = 0; tj < 8; ++tj) {
        const int col = wave * 128 + tj * 16 + lr;
        const float bias = bf[col];
        #pragma unroll
        for (int ti = 0; ti < 4; ++ti) {
            const long rg = row0 + ti * 16 + lq * 4;
            #pragma unroll
            for (int r = 0; r < 4; ++r) {
                float v = acc[ti][tj][r] + bias;
                v = fmaxf(v, 0.0f);
                h[(rg + r) * LDIM + col] = (f16)v;
            }
        }
    }
}

// ---------------- kernel 2: a/g GEMMs + gated score s ----------------
__device__ inline float fast_sigmoid(float xx) { return 1.0f / (1.0f + __expf(-xx)); }
__device__ inline float fast_tanh(float xx) {
    float e = __expf(-2.0f * fabsf(xx));
    float r = (1.0f - e) / (1.0f + e);
    return xx >= 0.0f ? r : -r;
}

// grid 625*3: rb=bx/3 (128 rows), cc=bx%3 (128 of 384 cols). bc omitted
// (constant shift, cancels in softmax over n).
__global__ __launch_bounds__(256, 2) void k_gemm2(
    const f16* __restrict__ h, const f16* __restrict__ WaT, const f16* __restrict__ WbT,
    const float* __restrict__ ba, const float* __restrict__ bb,
    const float* __restrict__ Wc, float* __restrict__ s)
{
    __shared__ __align__(16) f16 Hs [128 * 72];
    __shared__ __align__(16) f16 Bas[128 * 72];
    __shared__ __align__(16) f16 Bbs[128 * 72];
    const int tid = threadIdx.x;
    const int bx  = blockIdx.x;
    const int rb  = bx / 3;
    const int cc  = bx - rb * 3;
    const long row0 = (long)rb * 128;
    const int col0  = cc * 128;
    const int wave = tid >> 6, lane = tid & 63;
    const int wr = wave >> 1, wc = wave & 1;
    const int lr = lane & 15, lq = lane >> 4;

    floatx4 aacc[4][4] = {};
    floatx4 gacc[4][4] = {};

    for (int kt = 0; kt < 8; ++kt) {   // K=512, BK=64
        const int k0 = kt * 64;
        __syncthreads();
        #pragma unroll
        for (int rnd = 0; rnd < 4; ++rnd) {
            const int j  = rnd * 256 + tid;
            const int rr = j >> 3;
            const int kq = (j & 7) * 8;
            *(half8*)&Hs [rr * 72 + kq] = *(const half8*)&h  [(row0 + rr) * LDIM + k0 + kq];
            *(half8*)&Bas[rr * 72 + kq] = *(const half8*)&WaT[(long)(col0 + rr) * LDIM + k0 + kq];
            *(half8*)&Bbs[rr * 72 + kq] = *(const half8*)&WbT[(long)(col0 + rr) * LDIM + k0 + kq];
        }
        __syncthreads();
        #pragma unroll
        for (int kk = 0; kk < 2; ++kk) {
            const int kb = kk * 32 + lq * 8;
            half8 af[4];
            #pragma unroll
            for (int ti = 0; ti < 4; ++ti)
                af[ti] = *(const half8*)&Hs[(wr * 64 + ti * 16 + lr) * 72 + kb];
            #pragma unroll
            for (int tj = 0; tj < 4; ++tj) {
                half8 b1 = *(const half8*)&Bas[(wc * 64 + tj * 16 + lr) * 72 + kb];
                #pragma unroll
                for (int ti = 0; ti < 4; ++ti)
                    aacc[ti][tj] = __builtin_amdgcn_mfma_f32_16x16x32_f16(af[ti], b1, aacc[ti][tj], 0, 0, 0);
            }
            #pragma unroll
            for (int tj = 0; tj < 4; ++tj) {
                half8 b2 = *(const half8*)&Bbs[(wc * 64 + tj * 16 + lr) * 72 + kb];
                #pragma unroll
                for (int ti = 0; ti < 4; ++ti)
                    gacc[ti][tj] = __builtin_amdgcn_mfma_f32_16x16x32_f16(af[ti], b2, gacc[ti][tj], 0, 0, 0);
            }
        }
    }
    // epilogue: t = tanh(a+ba)*sigmoid(g+bb); s_row += sum_col t*Wc[col]
    float sp[4][4] = {};
    #pragma unroll
    for (int tj = 0; tj < 4; ++tj) {
        const int colg = col0 + wc * 64 + tj * 16 + lr;
        const float biasA = ba[colg];
        const float biasB = bb[colg];
        const float wcv   = Wc[colg];
        #pragma unroll
        for (int ti = 0; ti < 4; ++ti)
            #pragma unroll
            for (int r = 0; r < 4; ++r) {
                const float av = fast_tanh(aacc[ti][tj][r] + biasA);
                const float gv = fast_sigmoid(gacc[ti][tj][r] + biasB);
                sp[ti][r] += av * gv * wcv;
            }
    }
    #pragma unroll
    for (int m = 1; m < 16; m <<= 1)
        #pragma unroll
        for (int ti = 0; ti < 4; ++ti)
            #pragma unroll
            for (int r = 0; r < 4; ++r)
                sp[ti][r] += __shfl_xor(sp[ti][r], m, 64);
    if (lr == 0) {
        #pragma unroll
        for (int ti = 0; ti < 4; ++ti)
            #pragma unroll
            for (int r = 0; r < 4; ++r)
                atomicAdd(&s[row0 + wr * 64 + ti * 16 + lq * 4 + r], sp[ti][r]);
    }
}

// ---------------- kernel 3: per-batch softmax stats ----------------
__global__ void k_stats(const float* __restrict__ s, float* __restrict__ stats)
{
    const int b = blockIdx.x;
    const int tid = threadIdx.x; // 256
    const float* sb = s + b * NB;
    __shared__ float red[4];
    __shared__ float red2[4];
    __shared__ float smax_sh;
    float m = -3.4e38f;
    for (int i = tid; i < NB; i += 256) m = fmaxf(m, sb[i]);
    #pragma unroll
    for (int o = 32; o > 0; o >>= 1) m = fmaxf(m, __shfl_xor(m, o, 64));
    if ((tid & 63) == 0) red[tid >> 6] = m;
    __syncthreads();
    if (tid == 0) smax_sh = fmaxf(fmaxf(red[0], red[1]), fmaxf(red[2], red[3]));
    __syncthreads();
    const float smax = smax_sh;
    float sum = 0.0f;
    for (int i = tid; i < NB; i += 256) sum += __expf(sb[i] - smax);
    #pragma unroll
    for (int o = 32; o > 0; o >>= 1) sum += __shfl_xor(sum, o, 64);
    if ((tid & 63) == 0) red2[tid >> 6] = sum;
    __syncthreads();
    if (tid == 0) {
        stats[b * 2]     = smax;
        stats[b * 2 + 1] = red2[0] + red2[1] + red2[2] + red2[3];
    }
}

// ---------------- kernel 4: pooled += exp(s-max) * h ----------------
__global__ __launch_bounds__(256) void k_pool(
    const f16* __restrict__ h, const float* __restrict__ s,
    const float* __restrict__ stats, float* __restrict__ pooled)
{
    const int bx = blockIdx.x;        // 2 batches * 200 chunks
    const int b  = bx / 200;
    const int ch = bx - b * 200;
    const float smax = stats[b * 2];
    const long nbase = (long)b * NB + (long)ch * 200;
    const int c0 = threadIdx.x * 2;
    float a0 = 0.0f, a1 = 0.0f;
    for (int r = 0; r < 200; ++r) {
        const long n = nbase + r;
        const float w = __expf(s[n] - smax);
        half2v hv = *(const half2v*)&h[n * LDIM + c0];
        a0 += w * (float)hv[0];
        a1 += w * (float)hv[1];
    }
    atomicAdd(&pooled[b * LDIM + c0], a0);
    atomicAdd(&pooled[b * LDIM + c0 + 1], a1);
}

// ---------------- kernel 5: logits ----------------
__global__ void k_logits(const float* __restrict__ pooled, const float* __restrict__ stats,
                         const float* __restrict__ Wcls, const float* __restrict__ bcls,
                         float* __restrict__ out)
{
    const int tid = threadIdx.x;  // 256 = 4 waves; wave -> (b,c)
    const int wave = tid >> 6, lane = tid & 63;
    const int b = wave >> 1, c = wave & 1;
    float sum = 0.0f;
    for (int l = lane; l < LDIM; l += 64)
        sum += pooled[b * LDIM + l] * Wcls[l * 2 + c];
    #pragma unroll
    for (int o = 32; o > 0; o >>= 1) sum += __shfl_xor(sum, o, 64);
    if (lane == 0) out[b * 2 + c] = sum / stats[b * 2 + 1] + bcls[c];
}

// ---------------- launch ----------------
extern "C" void kernel_launch(void* const* d_in, const int* in_sizes, int n_in,
                              void* d_out, int out_size, void* d_ws, size_t ws_size,
                              hipStream_t stream)
{
    const float* x    = (const float*)d_in[0];
    const float* Wf   = (const float*)d_in[1];
    const float* bf   = (const float*)d_in[2];
    const float* Wa   = (const float*)d_in[3];
    const float* ba   = (const float*)d_in[4];
    const float* Wb   = (const float*)d_in[5];
    const float* bb   = (const float*)d_in[6];
    const float* Wc   = (const float*)d_in[7];
    // d_in[8] = bc: constant shift over n, cancels in softmax -> unused
    const float* Wcls = (const float*)d_in[9];
    const float* bcls = (const float*)d_in[10];
    float* out = (float*)d_out;

    // workspace layout (16B aligned), total 84,079,232 B
    char* w = (char*)d_ws;
    f16*   WfT    = (f16*)(w);                  // 1,048,576
    f16*   WaT    = (f16*)(w + 1048576);        //   393,216
    f16*   WbT    = (f16*)(w + 1441792);        //   393,216
    f16*   hbuf   = (f16*)(w + 1835008);        // 81,920,000
    float* sbuf   = (float*)(w + 83755008);     //   320,000
    float* stats  = (float*)(w + 84075008);     //       128
    float* pooled = (float*)(w + 84075136);     //     4,096

    hipMemsetAsync(sbuf, 0, 320000, stream);
    hipMemsetAsync(pooled, 0, 4096, stream);

    k_prep  <<<3584, 256, 0, stream>>>(Wf, Wa, Wb, WfT, WaT, WbT);
    k_gemm1 <<<M_TOTAL / 64, 256, 0, stream>>>(x, WfT, bf, hbuf);
    k_gemm2 <<<(M_TOTAL / 128) * 3, 256, 0, stream>>>(hbuf, WaT, WbT, ba, bb, Wc, sbuf);
    k_stats <<<2, 256, 0, stream>>>(sbuf, stats);
    k_pool  <<<400, 256, 0, stream>>>(hbuf, sbuf, stats, pooled);
    k_logits<<<1, 256, 0, stream>>>(pooled, stats, Wcls, bcls, out);
}